// Round 3
// baseline (330.881 us; speedup 1.0000x reference)
//
#include <hip/hip_runtime.h>

#define CUT 512
#define HH 4096
#define WW 4096

// Reference-exact coordinate math:
//   t = ((i+0.5)*s)/512 - 0.5 ; v = clip(off+t, off, off+s-1)
//   c0 = floor(v) ; c1 = min(c0+1, off+size-1) ; w = v - c0
__device__ __forceinline__ void coord(int i, int off, int size, float s,
                                      int& c0, int& c1, float& w) {
    float t = ((i + 0.5f) * s) / 512.0f - 0.5f;
    float offf = (float)off;
    float v = off + t;
    v = fminf(fmaxf(v, offf), offf + s - 1.0f);
    c0 = (int)floorf(v);
    c1 = min(c0 + 1, off + size - 1);
    w = v - (float)c0;
}

__device__ __forceinline__ void getParams(int imgI,
                                          const int* __restrict__ sizes,
                                          const int* __restrict__ offy,
                                          const int* __restrict__ offx,
                                          int& size, int& oy, int& ox) {
    if (imgI == 0) { size = 4096; oy = 0; ox = 0; }
    else { size = sizes[imgI - 1]; oy = offy[imgI - 1]; ox = offx[imgI - 1]; }
}

// ---------------------------------------------------------------------------
// Pass 1: horizontal lerp. One thread per (img, i, r, c, x_out).
// tmp[img][i][r][c][x] = img[c][y_r][x0]*(1-wx) + img[c][y_r][x1]*wx
// Exactly the reference's `top` (r=0) / `bot` (r=1) rows.
// ---------------------------------------------------------------------------
__global__ __launch_bounds__(256)
void pass1_kernel(const float* __restrict__ img,
                  const int* __restrict__ sizes,
                  const int* __restrict__ offy,
                  const int* __restrict__ offx,
                  float* __restrict__ tmp) {
    const int zz   = blockIdx.z;           // img*6 + r*3 + c
    const int imgI = zz / 6;
    const int rc   = zz % 6;
    const int r    = rc / 3;
    const int c    = rc % 3;
    const int i    = blockIdx.y;
    const int j    = blockIdx.x * 256 + threadIdx.x;

    int size, oy, ox;
    getParams(imgI, sizes, offy, offx, size, oy, ox);
    const float s = (float)size;

    int y0, y1; float wy;
    coord(i, oy, size, s, y0, y1, wy);
    const int yr = r ? y1 : y0;

    int x0, x1; float wx;
    coord(j, ox, size, s, x0, x1, wx);

    const float* p = img + (size_t)c * HH * WW + (size_t)yr * WW;
    float a = p[x0];
    float b = p[x1];
    float h = a * (1.0f - wx) + b * wx;

    tmp[((((size_t)imgI * CUT + i) * 2 + r) * 3 + c) * CUT + j] = h;
}

// ---------------------------------------------------------------------------
// Pass 2: vertical lerp + fan-out (overview -> 4 slots, crop0 -> gray).
// Fully coalesced reads of tmp and writes of out.
// ---------------------------------------------------------------------------
__global__ __launch_bounds__(256)
void pass2_kernel(const int* __restrict__ sizes,
                  const int* __restrict__ offy,
                  const int* __restrict__ offx,
                  const float* __restrict__ tmp,
                  float* __restrict__ out) {
    const int z = blockIdx.z;              // 0 = overview, 1..12 = crop z-1
    const int i = blockIdx.y;
    const int j = blockIdx.x * 256 + threadIdx.x;

    int size, oy, ox;
    getParams(z, sizes, offy, offx, size, oy, ox);
    const float s = (float)size;

    int y0, y1; float wy;
    coord(i, oy, size, s, y0, y1, wy);

    const size_t tbase = (((size_t)z * CUT + i) * 2) * 3 * CUT;  // r=0, c=0, x=0
    float v[3];
#pragma unroll
    for (int c = 0; c < 3; ++c) {
        float top = tmp[tbase + (size_t)c * CUT + j];
        float bot = tmp[tbase + (size_t)(3 + c) * CUT + j];
        v[c] = top * (1.0f - wy) + bot * wy;
    }

    const size_t imgStride = (size_t)3 * CUT * CUT;
    const size_t chStride  = (size_t)CUT * CUT;
    const size_t px = (size_t)i * CUT + j;

    if (z == 0) {
        float gray = v[0] * 0.2989f + v[1] * 0.587f + v[2] * 0.114f;
        const size_t pxf = (size_t)i * CUT + (CUT - 1 - j);
#pragma unroll
        for (int c = 0; c < 3; ++c) {
            out[0 * imgStride + c * chStride + px]  = v[c];
            out[1 * imgStride + c * chStride + px]  = gray;
            out[2 * imgStride + c * chStride + pxf] = v[c];
            out[3 * imgStride + c * chStride + pxf] = gray;
        }
    } else {
        const int k = z - 1;
        const size_t base = (size_t)(4 + k) * imgStride;
        if (k == 0) {
            float gray = v[0] * 0.2989f + v[1] * 0.587f + v[2] * 0.114f;
#pragma unroll
            for (int c = 0; c < 3; ++c)
                out[base + c * chStride + px] = gray;
        } else {
#pragma unroll
            for (int c = 0; c < 3; ++c)
                out[base + c * chStride + px] = v[c];
        }
    }
}

extern "C" void kernel_launch(void* const* d_in, const int* in_sizes, int n_in,
                              void* d_out, int out_size, void* d_ws, size_t ws_size,
                              hipStream_t stream) {
    const float* img  = (const float*)d_in[0];
    // d_in[1] = t (unused by the reference)
    const int* sizes  = (const int*)d_in[2];
    const int* offy   = (const int*)d_in[3];
    const int* offx   = (const int*)d_in[4];
    float* out = (float*)d_out;
    float* tmp = (float*)d_ws;   // 13*512*2*3*512 floats = ~82 MB

    dim3 block(256, 1, 1);
    dim3 grid1(CUT / 256, CUT, 13 * 6);   // (2, 512, 78)
    hipLaunchKernelGGL(pass1_kernel, grid1, block, 0, stream,
                       img, sizes, offy, offx, tmp);

    dim3 grid2(CUT / 256, CUT, 13);       // (2, 512, 13)
    hipLaunchKernelGGL(pass2_kernel, grid2, block, 0, stream,
                       sizes, offy, offx, tmp, out);
}

// Round 4
// 293.254 us; speedup vs baseline: 1.1283x; 1.1283x over previous
//
#include <hip/hip_runtime.h>

#define CUT 512
#define HH 4096
#define WW 4096

typedef float v2f __attribute__((ext_vector_type(2), aligned(4)));

// Reference-exact coordinate math:
//   t = ((i+0.5)*s)/512 - 0.5 ; v = clip(off+t, off, off+s-1)
//   c0 = floor(v) ; c1 = min(c0+1, off+size-1) ; w = v - c0
__device__ __forceinline__ void coord(int i, int off, int size, float s,
                                      int& c0, int& c1, float& w) {
    float t = ((i + 0.5f) * s) / 512.0f - 0.5f;
    float offf = (float)off;
    float v = off + t;
    v = fminf(fmaxf(v, offf), offf + s - 1.0f);
    c0 = (int)floorf(v);
    c1 = min(c0 + 1, off + size - 1);
    w = v - (float)c0;
}

__global__ __launch_bounds__(256)
void cutouts_kernel(const float* __restrict__ img,
                    const int* __restrict__ sizes,
                    const int* __restrict__ offy,
                    const int* __restrict__ offx,
                    float* __restrict__ out) {
    const int z = blockIdx.z;            // 0 = overview, 1..12 = crop z-1
    const int i = blockIdx.y;            // output row
    const int j = blockIdx.x * 256 + threadIdx.x;

    int size, oy, ox;
    if (z == 0) { size = 4096; oy = 0; ox = 0; }
    else        { size = sizes[z - 1]; oy = offy[z - 1]; ox = offx[z - 1]; }
    const float s = (float)size;

    int y0, y1; float wy;
    coord(i, oy, size, s, y0, y1, wy);
    int x0, x1; float wx;
    coord(j, ox, size, s, x0, x1, wx);

    // Pair-load trick: taps (x0, x0+1) as one unaligned dwordx2.
    // At the right clamp (x0 == ox+size-1) wx==0, so tap b is a don't-care;
    // shift the pair left one to stay in-bounds and take a = pair.y.
    const bool xe = (x0 >= ox + size - 1);
    const int  xb = xe ? x0 - 1 : x0;    // size >= 512 so xb >= ox >= 0

    float v[3];
#pragma unroll
    for (int c = 0; c < 3; ++c) {
        const float* base = img + (size_t)c * HH * WW;
        const float* r0 = base + (size_t)y0 * WW + xb;
        const float* r1 = base + (size_t)y1 * WW + xb;
        v2f t2 = *(const v2f*)r0;
        v2f b2 = *(const v2f*)r1;
        float a  = xe ? t2.y : t2.x;
        float b  = t2.y;
        float cc = xe ? b2.y : b2.x;
        float d  = b2.y;
        float top = a  * (1.0f - wx) + b * wx;
        float bot = cc * (1.0f - wx) + d * wx;
        v[c] = top * (1.0f - wy) + bot * wy;
    }

    const size_t imgStride = (size_t)3 * CUT * CUT;
    const size_t chStride  = (size_t)CUT * CUT;
    const size_t px = (size_t)i * CUT + j;

    if (z == 0) {
        float gray = v[0] * 0.2989f + v[1] * 0.587f + v[2] * 0.114f;
        const size_t pxf = (size_t)i * CUT + (CUT - 1 - j);
#pragma unroll
        for (int c = 0; c < 3; ++c) {
            __builtin_nontemporal_store(v[c],  &out[0 * imgStride + c * chStride + px]);
            __builtin_nontemporal_store(gray,  &out[1 * imgStride + c * chStride + px]);
            __builtin_nontemporal_store(v[c],  &out[2 * imgStride + c * chStride + pxf]);
            __builtin_nontemporal_store(gray,  &out[3 * imgStride + c * chStride + pxf]);
        }
    } else {
        const int k = z - 1;
        const size_t base = (size_t)(4 + k) * imgStride;
        if (k == 0) {
            float gray = v[0] * 0.2989f + v[1] * 0.587f + v[2] * 0.114f;
#pragma unroll
            for (int c = 0; c < 3; ++c)
                __builtin_nontemporal_store(gray, &out[base + c * chStride + px]);
        } else {
#pragma unroll
            for (int c = 0; c < 3; ++c)
                __builtin_nontemporal_store(v[c], &out[base + c * chStride + px]);
        }
    }
}

extern "C" void kernel_launch(void* const* d_in, const int* in_sizes, int n_in,
                              void* d_out, int out_size, void* d_ws, size_t ws_size,
                              hipStream_t stream) {
    const float* img  = (const float*)d_in[0];
    // d_in[1] = t (unused by the reference)
    const int* sizes  = (const int*)d_in[2];
    const int* offy   = (const int*)d_in[3];
    const int* offx   = (const int*)d_in[4];
    float* out = (float*)d_out;

    dim3 block(256, 1, 1);
    dim3 grid(CUT / 256, CUT, 13);   // (2, 512, 13)
    hipLaunchKernelGGL(cutouts_kernel, grid, block, 0, stream,
                       img, sizes, offy, offx, out);
}

// Round 5
// 292.611 us; speedup vs baseline: 1.1308x; 1.0022x over previous
//
#include <hip/hip_runtime.h>

#define CUT 512
#define HH 4096
#define WW 4096

typedef float v2f __attribute__((ext_vector_type(2), aligned(4)));

// Reference-exact coordinate math:
//   t = ((i+0.5)*s)/512 - 0.5 ; v = clip(off+t, off, off+s-1)
//   c0 = floor(v) ; c1 = min(c0+1, off+size-1) ; w = v - c0
__device__ __forceinline__ void coord(int i, int off, int size, float s,
                                      int& c0, int& c1, float& w) {
    float t = ((i + 0.5f) * s) / 512.0f - 0.5f;
    float offf = (float)off;
    float v = off + t;
    v = fminf(fmaxf(v, offf), offf + s - 1.0f);
    c0 = (int)floorf(v);
    c1 = min(c0 + 1, off + size - 1);
    w = v - (float)c0;
}

// Two output pixels per thread (j, j+256): 12 pair-loads issued up front for
// max memory-level parallelism, then consumed.
__global__ __launch_bounds__(256)
void cutouts_kernel(const float* __restrict__ img,
                    const int* __restrict__ sizes,
                    const int* __restrict__ offy,
                    const int* __restrict__ offx,
                    float* __restrict__ out) {
    const int z = blockIdx.z;            // 0 = overview, 1..12 = crop z-1
    const int i = blockIdx.y;            // output row
    const int tid = threadIdx.x;

    int size, oy, ox;
    if (z == 0) { size = 4096; oy = 0; ox = 0; }
    else        { size = sizes[z - 1]; oy = offy[z - 1]; ox = offx[z - 1]; }
    const float s = (float)size;

    int y0, y1; float wy;
    coord(i, oy, size, s, y0, y1, wy);

    int j[2]   = { tid, tid + 256 };
    int xb[2];  bool xe[2];  float wx[2];
#pragma unroll
    for (int p = 0; p < 2; ++p) {
        int x0, x1;
        coord(j[p], ox, size, s, x0, x1, wx[p]);
        // Pair-load trick: taps (x0, x0+1) as one unaligned dwordx2. At the
        // right clamp wx==0 so tap b is a don't-care; shift pair left one.
        xe[p] = (x0 >= ox + size - 1);
        xb[p] = xe[p] ? x0 - 1 : x0;
    }

    // Issue all 12 loads before any use.
    v2f t2[2][3], b2[2][3];
#pragma unroll
    for (int c = 0; c < 3; ++c) {
        const float* base = img + (size_t)c * HH * WW;
        const float* r0 = base + (size_t)y0 * WW;
        const float* r1 = base + (size_t)y1 * WW;
#pragma unroll
        for (int p = 0; p < 2; ++p) {
            t2[p][c] = *(const v2f*)(r0 + xb[p]);
            b2[p][c] = *(const v2f*)(r1 + xb[p]);
        }
    }

    const size_t imgStride = (size_t)3 * CUT * CUT;
    const size_t chStride  = (size_t)CUT * CUT;

#pragma unroll
    for (int p = 0; p < 2; ++p) {
        float v[3];
#pragma unroll
        for (int c = 0; c < 3; ++c) {
            float a  = xe[p] ? t2[p][c].y : t2[p][c].x;
            float b  = t2[p][c].y;
            float cc = xe[p] ? b2[p][c].y : b2[p][c].x;
            float d  = b2[p][c].y;
            float top = a  * (1.0f - wx[p]) + b * wx[p];
            float bot = cc * (1.0f - wx[p]) + d * wx[p];
            v[c] = top * (1.0f - wy) + bot * wy;
        }

        const size_t px = (size_t)i * CUT + j[p];
        if (z == 0) {
            float gray = v[0] * 0.2989f + v[1] * 0.587f + v[2] * 0.114f;
            const size_t pxf = (size_t)i * CUT + (CUT - 1 - j[p]);
#pragma unroll
            for (int c = 0; c < 3; ++c) {
                __builtin_nontemporal_store(v[c], &out[0 * imgStride + c * chStride + px]);
                __builtin_nontemporal_store(gray, &out[1 * imgStride + c * chStride + px]);
                __builtin_nontemporal_store(v[c], &out[2 * imgStride + c * chStride + pxf]);
                __builtin_nontemporal_store(gray, &out[3 * imgStride + c * chStride + pxf]);
            }
        } else {
            const int k = z - 1;
            const size_t base = (size_t)(4 + k) * imgStride;
            if (k == 0) {
                float gray = v[0] * 0.2989f + v[1] * 0.587f + v[2] * 0.114f;
#pragma unroll
                for (int c = 0; c < 3; ++c)
                    __builtin_nontemporal_store(gray, &out[base + c * chStride + px]);
            } else {
#pragma unroll
                for (int c = 0; c < 3; ++c)
                    __builtin_nontemporal_store(v[c], &out[base + c * chStride + px]);
            }
        }
    }
}

extern "C" void kernel_launch(void* const* d_in, const int* in_sizes, int n_in,
                              void* d_out, int out_size, void* d_ws, size_t ws_size,
                              hipStream_t stream) {
    const float* img  = (const float*)d_in[0];
    // d_in[1] = t (unused by the reference)
    const int* sizes  = (const int*)d_in[2];
    const int* offy   = (const int*)d_in[3];
    const int* offx   = (const int*)d_in[4];
    float* out = (float*)d_out;

    dim3 block(256, 1, 1);
    dim3 grid(1, CUT, 13);   // 2 px/thread in x
    hipLaunchKernelGGL(cutouts_kernel, grid, block, 0, stream,
                       img, sizes, offy, offx, out);
}